// Round 12
// baseline (1925.419 us; speedup 1.0000x reference)
//
#include <hip/hip_runtime.h>
#include <hip/hip_bf16.h>

// LSTM: B=64, T=2048, D=128, H=128, gates 4H=512.
//  K0: wxt pre-kernel: Wx f32[128][512] -> bf16 wxt[col][k]
//  K1: xg GEMM via bf16 MFMA (R11, passed)
//  K2: RNN, 32 blocks x 512 threads, TWO batches per block sharing the same
//      64-VGPR Wh fragment set (weights are batch-independent -- the R9
//      mistake was duplicating them at 1024 threads). Per macro-step:
//      32 MFMA (two independent 16-chains) + 2 independent VALU chains +
//      ONE barrier -> batch1 MFMA issue hides batch0 chain latency; DS and
//      barrier fixed costs amortize over 2 batch-steps.
//      R11 lesson: chain split + setprio regressed; reverted to R8 core.

#define B_ 64
#define T_ 2048
#define D_ 128
#define H_ 128
#define G_ 512  // 4*H

typedef __bf16 v8bf __attribute__((ext_vector_type(8)));
typedef float f32x4 __attribute__((ext_vector_type(4)));

__device__ __forceinline__ float fast_exp2(float x) { return __builtin_amdgcn_exp2f(x); }
__device__ __forceinline__ float fast_rcp(float x)  { return __builtin_amdgcn_rcpf(x); }
__device__ __forceinline__ float sigmoid_(float x) {
    return fast_rcp(1.0f + fast_exp2(x * -1.44269504088896341f));
}
__device__ __forceinline__ float tanh_(float x) {
    // tanh(x) = 1 - 2/(1+2^(x*2*log2e)); saturates correctly at +-inf.
    return 1.0f - 2.0f * fast_rcp(1.0f + fast_exp2(x * 2.88539008177792682f));
}
__device__ __forceinline__ unsigned short f2bf(float f) {
    union { float f; unsigned u; } v; v.f = f;
    unsigned r = v.u + 0x7FFFu + ((v.u >> 16) & 1u);  // RNE
    return (unsigned short)(r >> 16);
}

// ---------------- K0: Wx -> bf16 transposed wxt[col][k] ----------------
__global__ void __launch_bounds__(256)
wxt_kernel(const float* __restrict__ Wx, unsigned short* __restrict__ wxt) {
    int t = blockIdx.x * 256 + threadIdx.x;   // 0..8191
    int col = t >> 4;            // 0..511
    int k0  = (t & 15) * 8;      // 0..120
    union { unsigned short s[8]; v8bf v; } u;
#pragma unroll
    for (int j = 0; j < 8; ++j) u.s[j] = f2bf(Wx[(size_t)(k0 + j) * G_ + col]);
    *(v8bf*)&wxt[(size_t)col * D_ + k0] = u.v;
}

// ---------------- K1: xg GEMM via MFMA ----------------
__global__ void __launch_bounds__(256)
xg_gemm_mfma(const float* __restrict__ x, const unsigned short* __restrict__ wxt,
             const float* __restrict__ bias, float* __restrict__ xg,
             int t0, int C) {
    const int tid  = threadIdx.x;
    const int w    = tid >> 6;
    const int lane = tid & 63;
    const int q    = lane >> 4;
    const int cl   = lane & 15;
    const int kb   = q * 8;

    const int block_row = blockIdx.x * 16;     // in [0, B*C)
    const int b  = block_row / C;
    const int tl = block_row - b * C;

    const float* xr = x + ((size_t)b * T_ + (size_t)(t0 + tl) + cl) * D_;
    v8bf af[4];
#pragma unroll
    for (int kk = 0; kk < 4; ++kk) {
        float4 lo = *(const float4*)&xr[kk * 32 + kb];
        float4 hi = *(const float4*)&xr[kk * 32 + kb + 4];
        union { unsigned u[4]; v8bf v; } pk;
        asm("v_cvt_pk_bf16_f32 %0, %1, %2" : "=v"(pk.u[0]) : "v"(lo.x), "v"(lo.y));
        asm("v_cvt_pk_bf16_f32 %0, %1, %2" : "=v"(pk.u[1]) : "v"(lo.z), "v"(lo.w));
        asm("v_cvt_pk_bf16_f32 %0, %1, %2" : "=v"(pk.u[2]) : "v"(hi.x), "v"(hi.y));
        asm("v_cvt_pk_bf16_f32 %0, %1, %2" : "=v"(pk.u[3]) : "v"(hi.z), "v"(hi.w));
        af[kk] = pk.v;
    }

    f32x4 acc[8];
#pragma unroll
    for (int n = 0; n < 8; ++n) {
        float bv = bias[w * 128 + n * 16 + cl];
        acc[n] = (f32x4){bv, bv, bv, bv};
    }

#pragma unroll
    for (int kk = 0; kk < 4; ++kk) {
#pragma unroll
        for (int n = 0; n < 8; ++n) {
            v8bf bf = *(const v8bf*)&wxt[(size_t)(w * 128 + n * 16 + cl) * D_ + kk * 32 + kb];
            acc[n] = __builtin_amdgcn_mfma_f32_16x16x32_bf16(af[kk], bf, acc[n], 0, 0, 0);
        }
    }

#pragma unroll
    for (int n = 0; n < 8; ++n) {
        int col = w * 128 + n * 16 + cl;
#pragma unroll
        for (int r = 0; r < 4; ++r)
            xg[(size_t)(block_row + q * 4 + r) * G_ + col] = acc[n][r];
    }
}

// ---------------- K2: recurrence via MFMA, 2 batches/block ----------------
__global__ void __launch_bounds__(512)
__attribute__((amdgpu_waves_per_eu(2, 2)))
lstm_rnn_mfma(const float* __restrict__ xg, const float* __restrict__ Wh,
              float* __restrict__ hs, float* __restrict__ cs,
              float* __restrict__ hstate, float* __restrict__ cstate,
              int t0, int C) {
    const int tid  = threadIdx.x;
    const int w    = tid >> 6;     // wave 0..7
    const int lane = tid & 63;
    const int q    = lane >> 4;    // k-quarter
    const int cl   = lane & 15;
    const int kb   = q * 8;
    const int hu   = w * 16 + cl;  // hidden unit owned
    const int b0   = blockIdx.x * 2;
    const int b1   = b0 + 1;

    __shared__ __align__(16) unsigned short h0_[2][H_];
    __shared__ __align__(16) unsigned short h1_[2][H_];

    // one-time: Wh B-fragments (16 frags = 64 VGPRs), shared by both batches
    v8bf whf[4][4];
#pragma unroll
    for (int kk = 0; kk < 4; ++kk) {
#pragma unroll
        for (int gc = 0; gc < 4; ++gc) {
            union { unsigned short s[8]; v8bf v; } uw;
#pragma unroll
            for (int j = 0; j < 8; ++j)
                uw.s[j] = f2bf(Wh[(size_t)(kk * 32 + kb + j) * G_ + gc * 128 + hu]);
            whf[kk][gc] = uw.v;
        }
    }

    float c0 = 0.0f, c1 = 0.0f;
    if (t0 > 0) { c0 = cstate[b0 * H_ + hu]; c1 = cstate[b1 * H_ + hu]; }
    if (tid < H_) {
        h0_[0][tid] = f2bf((t0 > 0) ? hstate[b0 * H_ + tid] : 0.0f);
        h1_[0][tid] = f2bf((t0 > 0) ? hstate[b1 * H_ + tid] : 0.0f);
    }
    __syncthreads();  // once per chunk

    const float* xg0 = xg + (size_t)b0 * C * G_;
    const float* xg1 = xg + (size_t)b1 * C * G_;

    // 2-deep xg prefetch: slot A = even t, slot B = odd t, per batch.
    float pA00, pA01, pA02, pA03, pA10, pA11, pA12, pA13;
    float pB00, pB01, pB02, pB03, pB10, pB11, pB12, pB13;
    {
        const float* x0 = xg0;            const float* x1 = xg1;
        pA00 = x0[hu]; pA01 = x0[128+hu]; pA02 = x0[256+hu]; pA03 = x0[384+hu];
        pA10 = x1[hu]; pA11 = x1[128+hu]; pA12 = x1[256+hu]; pA13 = x1[384+hu];
        x0 = xg0 + G_;                    x1 = xg1 + G_;
        pB00 = x0[hu]; pB01 = x0[128+hu]; pB02 = x0[256+hu]; pB03 = x0[384+hu];
        pB10 = x1[hu]; pB11 = x1[128+hu]; pB12 = x1[256+hu]; pB13 = x1[384+hu];
    }

#define RNN_STEP2(X00, X01, X02, X03, X10, X11, X12, X13, TCUR, PR, PW)        \
    {                                                                          \
        f32x4 a00 = {0,0,0,0}, a01 = {0,0,0,0}, a02 = {0,0,0,0}, a03 = {0,0,0,0}; \
        f32x4 a10 = {0,0,0,0}, a11 = {0,0,0,0}, a12 = {0,0,0,0}, a13 = {0,0,0,0}; \
        _Pragma("unroll")                                                      \
        for (int kk = 0; kk < 4; ++kk) {                                       \
            v8bf ha0 = *(const v8bf*)&h0_[PR][kk * 32 + kb];                   \
            a00 = __builtin_amdgcn_mfma_f32_16x16x32_bf16(ha0, whf[kk][0], a00, 0, 0, 0); \
            a01 = __builtin_amdgcn_mfma_f32_16x16x32_bf16(ha0, whf[kk][1], a01, 0, 0, 0); \
            a02 = __builtin_amdgcn_mfma_f32_16x16x32_bf16(ha0, whf[kk][2], a02, 0, 0, 0); \
            a03 = __builtin_amdgcn_mfma_f32_16x16x32_bf16(ha0, whf[kk][3], a03, 0, 0, 0); \
        }                                                                      \
        _Pragma("unroll")                                                      \
        for (int kk = 0; kk < 4; ++kk) {                                       \
            v8bf ha1 = *(const v8bf*)&h1_[PR][kk * 32 + kb];                   \
            a10 = __builtin_amdgcn_mfma_f32_16x16x32_bf16(ha1, whf[kk][0], a10, 0, 0, 0); \
            a11 = __builtin_amdgcn_mfma_f32_16x16x32_bf16(ha1, whf[kk][1], a11, 0, 0, 0); \
            a12 = __builtin_amdgcn_mfma_f32_16x16x32_bf16(ha1, whf[kk][2], a12, 0, 0, 0); \
            a13 = __builtin_amdgcn_mfma_f32_16x16x32_bf16(ha1, whf[kk][3], a13, 0, 0, 0); \
        }                                                                      \
        {   /* batch0 VALU chain */                                            \
            float iv = sigmoid_(a00[0] + X00);                                 \
            float fv = sigmoid_(a01[0] + X01);                                 \
            float gv = tanh_(a02[0] + X02);                                    \
            float ov = sigmoid_(a03[0] + X03);                                 \
            c0 = fmaf(fv, c0, iv * gv);                                        \
            float hnv = ov * tanh_(c0);                                        \
            if (q == 0) {                                                      \
                h0_[PW][hu] = f2bf(hnv);                                       \
                size_t off = ((size_t)b0 * T_ + (size_t)(t0 + (TCUR))) * H_ + hu; \
                hs[off] = hnv; cs[off] = c0;                                   \
            }                                                                  \
        }                                                                      \
        {   /* batch1 VALU chain */                                            \
            float iv = sigmoid_(a10[0] + X10);                                 \
            float fv = sigmoid_(a11[0] + X11);                                 \
            float gv = tanh_(a12[0] + X12);                                    \
            float ov = sigmoid_(a13[0] + X13);                                 \
            c1 = fmaf(fv, c1, iv * gv);                                        \
            float hnv = ov * tanh_(c1);                                        \
            if (q == 0) {                                                      \
                h1_[PW][hu] = f2bf(hnv);                                       \
                size_t off = ((size_t)b1 * T_ + (size_t)(t0 + (TCUR))) * H_ + hu; \
                hs[off] = hnv; cs[off] = c1;                                   \
            }                                                                  \
        }                                                                      \
        { /* reload this prefetch slot for step TCUR+2 */                      \
          int pf = ((TCUR) + 2 < C) ? ((TCUR) + 2) : (C - 1);                  \
          const float* x0_ = xg0 + (size_t)pf * G_;                            \
          const float* x1_ = xg1 + (size_t)pf * G_;                            \
          X00 = x0_[hu];       X01 = x0_[128 + hu];                            \
          X02 = x0_[256 + hu]; X03 = x0_[384 + hu];                            \
          X10 = x1_[hu];       X11 = x1_[128 + hu];                            \
          X12 = x1_[256 + hu]; X13 = x1_[384 + hu]; }                          \
        asm volatile("s_waitcnt lgkmcnt(0)\n\ts_barrier" ::: "memory");        \
    }

    for (int t = 0; t < C; t += 2) {  // C is a multiple of 64
        RNN_STEP2(pA00, pA01, pA02, pA03, pA10, pA11, pA12, pA13, t,     0, 1)
        RNN_STEP2(pB00, pB01, pB02, pB03, pB10, pB11, pB12, pB13, t + 1, 1, 0)
    }
#undef RNN_STEP2

    if (q == 0) { cstate[b0 * H_ + hu] = c0; cstate[b1 * H_ + hu] = c1; }
    // final h in buf 0 (C even; last step wrote PW=0)
    if (tid < H_) {
        unsigned u0 = ((unsigned)h0_[0][tid]) << 16;
        unsigned u1 = ((unsigned)h1_[0][tid]) << 16;
        float f0, f1;
        __builtin_memcpy(&f0, &u0, 4); __builtin_memcpy(&f1, &u1, 4);
        hstate[b0 * H_ + tid] = f0;
        hstate[b1 * H_ + tid] = f1;
    }
}

extern "C" void kernel_launch(void* const* d_in, const int* in_sizes, int n_in,
                              void* d_out, int out_size, void* d_ws, size_t ws_size,
                              hipStream_t stream) {
    const float* x    = (const float*)d_in[0];  // [64,2048,128]
    const float* Wx   = (const float*)d_in[1];  // [128,512]
    const float* Wh   = (const float*)d_in[2];  // [128,512]
    const float* bias = (const float*)d_in[3];  // [512]

    float* hs = (float*)d_out;                         // [64,2048,128]
    float* cs = hs + (size_t)B_ * T_ * H_;             // [64,2048,128]

    float* hstate = (float*)d_ws;                      // [64,128]
    float* cstate = hstate + B_ * H_;                  // [64,128]
    unsigned short* wxt = (unsigned short*)(cstate + B_ * H_);  // [512][128] bf16
    float* xg = (float*)(wxt + (size_t)G_ * D_);       // chunk scratch [B][C][512]

    const size_t head_bytes = (size_t)2 * B_ * H_ * 4 + (size_t)G_ * D_ * 2;
    size_t avail_bytes = (ws_size > head_bytes) ? (ws_size - head_bytes) : 0;
    const size_t bytes_per_t = (size_t)B_ * G_ * sizeof(float);

    int C = (int)(avail_bytes / bytes_per_t);
    if (C > T_) C = T_;
    C &= ~63;
    if (C < 64) C = 64;

    wxt_kernel<<<32, 256, 0, stream>>>(Wx, wxt);

    for (int t0 = 0; t0 < T_; t0 += C) {
        int Ci = (T_ - t0 < C) ? (T_ - t0) : C;
        dim3 ggrid((B_ * Ci) / 16);
        xg_gemm_mfma<<<ggrid, 256, 0, stream>>>(x, wxt, bias, xg, t0, Ci);
        lstm_rnn_mfma<<<B_ / 2, 512, 0, stream>>>(xg, Wh, hs, cs, hstate, cstate, t0, Ci);
    }
}

// Round 14
// 956.450 us; speedup vs baseline: 2.0131x; 2.0131x over previous
//
#include <hip/hip_runtime.h>
#include <hip/hip_bf16.h>

// LSTM: B=64, T=2048, D=128, H=128, gates 4H=512.
// R13 lesson: intra-kernel producer->consumer flags are racy (replay-level
// nondeterminism). This version overlaps GEMM and RNN with ZERO cross-block
// sync: chunked pipeline, xg double-buffered in ws.
//   launch i: grid = 64 RNN blocks (chunk i, reads buf[i&1])
//           + GEMM blocks (chunk i+1, writes buf[(i+1)&1])   <- independent!
// GEMM(c) -> RNN(c) ordering rides on kernel-launch boundaries (coherent).
// RNN core = R8-exact (proven 1030us) + gate-packed xg [t][hu][4] so each
// step does ONE global_load_dwordx4 instead of 4 scalar loads.

#define B_ 64
#define T_ 2048
#define D_ 128
#define H_ 128
#define G_ 512  // 4*H

typedef __bf16 v8bf __attribute__((ext_vector_type(8)));
typedef float f32x4 __attribute__((ext_vector_type(4)));

__device__ __forceinline__ float fast_exp2(float x) { return __builtin_amdgcn_exp2f(x); }
__device__ __forceinline__ float fast_rcp(float x)  { return __builtin_amdgcn_rcpf(x); }
__device__ __forceinline__ float sigmoid_(float x) {
    return fast_rcp(1.0f + fast_exp2(x * -1.44269504088896341f));
}
__device__ __forceinline__ float tanh_(float x) {
    // tanh(x) = 1 - 2/(1+2^(x*2*log2e)); saturates correctly at +-inf.
    return 1.0f - 2.0f * fast_rcp(1.0f + fast_exp2(x * 2.88539008177792682f));
}
__device__ __forceinline__ unsigned short f2bf(float f) {
    union { float f; unsigned u; } v; v.f = f;
    unsigned r = v.u + 0x7FFFu + ((v.u >> 16) & 1u);  // RNE
    return (unsigned short)(r >> 16);
}

// ---------------- K0: Wx -> bf16 transposed wxt[col][k] ----------------
__global__ void __launch_bounds__(256)
wxt_kernel(const float* __restrict__ Wx, unsigned short* __restrict__ wxt) {
    int t = blockIdx.x * 256 + threadIdx.x;   // 0..8191
    int col = t >> 4;            // 0..511
    int k0  = (t & 15) * 8;      // 0..120
    union { unsigned short s[8]; v8bf v; } u;
#pragma unroll
    for (int j = 0; j < 8; ++j) u.s[j] = f2bf(Wx[(size_t)(k0 + j) * G_ + col]);
    *(v8bf*)&wxt[(size_t)col * D_ + k0] = u.v;
}

// ---------------- device GEMM: one 32-row block (512 threads) ----------------
// Output layout GATE-PACKED: xg[row*512 + hu*4 + gate], gate order i,f,g,o.
__device__ __forceinline__ void gemm32(const float* __restrict__ x,
                                       const unsigned short* __restrict__ wxt,
                                       const float* __restrict__ bias,
                                       float* __restrict__ xg,
                                       int t0g, int Cg, int gb, int tid) {
    const int lane = tid & 63;
    const int q    = lane >> 4;
    const int cl   = lane & 15;
    const int kb   = q * 8;
    const int wave = tid >> 6;
    const int half = wave >> 2;    // 0/1: which 16-row tile
    const int w4   = wave & 3;     // gate quarter = gate index
    const int rowg = gb * 32 + half * 16;   // chunk-local row
    const int b    = rowg / Cg;             // Cg multiple of 64
    const int tl   = rowg - b * Cg;

    const float* xr = x + ((size_t)b * T_ + (size_t)(t0g + tl) + cl) * D_;
    v8bf af[4];
#pragma unroll
    for (int kk = 0; kk < 4; ++kk) {
        float4 lo = *(const float4*)&xr[kk * 32 + kb];
        float4 hi = *(const float4*)&xr[kk * 32 + kb + 4];
        union { unsigned u[4]; v8bf v; } pk;
        asm("v_cvt_pk_bf16_f32 %0, %1, %2" : "=v"(pk.u[0]) : "v"(lo.x), "v"(lo.y));
        asm("v_cvt_pk_bf16_f32 %0, %1, %2" : "=v"(pk.u[1]) : "v"(lo.z), "v"(lo.w));
        asm("v_cvt_pk_bf16_f32 %0, %1, %2" : "=v"(pk.u[2]) : "v"(hi.x), "v"(hi.y));
        asm("v_cvt_pk_bf16_f32 %0, %1, %2" : "=v"(pk.u[3]) : "v"(hi.z), "v"(hi.w));
        af[kk] = pk.v;
    }

    f32x4 acc[8];
#pragma unroll
    for (int n = 0; n < 8; ++n) {
        float bv = bias[w4 * 128 + n * 16 + cl];
        acc[n] = (f32x4){bv, bv, bv, bv};
    }
#pragma unroll
    for (int kk = 0; kk < 4; ++kk) {
#pragma unroll
        for (int n = 0; n < 8; ++n) {
            v8bf bf = *(const v8bf*)&wxt[(size_t)(w4 * 128 + n * 16 + cl) * D_ + kk * 32 + kb];
            acc[n] = __builtin_amdgcn_mfma_f32_16x16x32_bf16(af[kk], bf, acc[n], 0, 0, 0);
        }
    }
#pragma unroll
    for (int n = 0; n < 8; ++n) {
        int hu = n * 16 + cl;
#pragma unroll
        for (int r = 0; r < 4; ++r)
            xg[(size_t)(rowg + q * 4 + r) * G_ + hu * 4 + w4] = acc[n][r];
    }
}

// ---------------- standalone GEMM kernel (chunk 0) ----------------
__global__ void __launch_bounds__(512)
xg_gemm512(const float* __restrict__ x, const unsigned short* __restrict__ wxt,
           const float* __restrict__ bias, float* __restrict__ xg,
           int t0g, int Cg) {
    gemm32(x, wxt, bias, xg, t0g, Cg, blockIdx.x, threadIdx.x);
}

// ---------------- fused: RNN(chunk cur) + GEMM(chunk next) ----------------
__global__ void __launch_bounds__(512)
__attribute__((amdgpu_waves_per_eu(2, 2)))
lstm_fused(const float* __restrict__ x, const unsigned short* __restrict__ wxt,
           const float* __restrict__ Wh, const float* __restrict__ bias,
           float* __restrict__ hs, float* __restrict__ cs,
           float* __restrict__ hstate, float* __restrict__ cstate,
           const float* __restrict__ xgCur, float* __restrict__ xgNext,
           int t0, int C, int t0n, int Cn) {
    const int tid  = threadIdx.x;
    const int lane = tid & 63;
    const int q    = lane >> 4;
    const int cl   = lane & 15;
    const int kb   = q * 8;

    if (blockIdx.x >= 64) {
        // GEMM role: produce NEXT chunk's xg. No dependency on RNN blocks.
        gemm32(x, wxt, bias, xgNext, t0n, Cn, blockIdx.x - 64, tid);
        return;
    }

    // ================= RNN role: R8 core, packed xg loads =================
    const int b  = blockIdx.x;
    const int w  = tid >> 6;       // wave 0..7
    const int hu = w * 16 + cl;    // hidden unit owned

    __shared__ __align__(16) unsigned short h_u16[2][H_];

    // one-time: Wh B-fragments (16 frags = 64 VGPRs)
    v8bf whf[4][4];
#pragma unroll
    for (int kk = 0; kk < 4; ++kk) {
#pragma unroll
        for (int gc = 0; gc < 4; ++gc) {
            union { unsigned short s[8]; v8bf v; } uw;
#pragma unroll
            for (int j = 0; j < 8; ++j)
                uw.s[j] = f2bf(Wh[(size_t)(kk * 32 + kb + j) * G_ + gc * 128 + hu]);
            whf[kk][gc] = uw.v;
        }
    }

    float c = 0.0f;
    if (t0 > 0) c = cstate[b * H_ + hu];
    if (tid < H_) h_u16[0][tid] = f2bf((t0 > 0) ? hstate[b * H_ + tid] : 0.0f);
    __syncthreads();  // once per chunk

    const float* xgb = xgCur + (size_t)b * C * G_;

    // 4-step-deep xg prefetch, ONE dwordx4 per step (gate-packed layout)
    f32x4 xp0 = *(const f32x4*)&xgb[(size_t)0 * G_ + hu * 4];
    f32x4 xp1 = *(const f32x4*)&xgb[(size_t)1 * G_ + hu * 4];
    f32x4 xp2 = *(const f32x4*)&xgb[(size_t)2 * G_ + hu * 4];
    f32x4 xp3 = *(const f32x4*)&xgb[(size_t)3 * G_ + hu * 4];

#define RNN_STEP(PX, TCUR, PR, PW)                                             \
    {                                                                          \
        f32x4 a0 = {0.f, 0.f, 0.f, 0.f};                                       \
        f32x4 a1 = {0.f, 0.f, 0.f, 0.f};                                       \
        f32x4 a2 = {0.f, 0.f, 0.f, 0.f};                                       \
        f32x4 a3 = {0.f, 0.f, 0.f, 0.f};                                       \
        _Pragma("unroll")                                                      \
        for (int kk = 0; kk < 4; ++kk) {                                       \
            v8bf ha = *(const v8bf*)&h_u16[PR][kk * 32 + kb];                  \
            a0 = __builtin_amdgcn_mfma_f32_16x16x32_bf16(ha, whf[kk][0], a0, 0, 0, 0); \
            a1 = __builtin_amdgcn_mfma_f32_16x16x32_bf16(ha, whf[kk][1], a1, 0, 0, 0); \
            a2 = __builtin_amdgcn_mfma_f32_16x16x32_bf16(ha, whf[kk][2], a2, 0, 0, 0); \
            a3 = __builtin_amdgcn_mfma_f32_16x16x32_bf16(ha, whf[kk][3], a3, 0, 0, 0); \
        }                                                                      \
        float iv = sigmoid_(a0[0] + PX.x);                                     \
        float fv = sigmoid_(a1[0] + PX.y);                                     \
        float gv = tanh_(a2[0] + PX.z);                                        \
        float ov = sigmoid_(a3[0] + PX.w);                                     \
        c = fmaf(fv, c, iv * gv);                                              \
        float hnv = ov * tanh_(c);                                             \
        { int pf = ((TCUR) + 4 < C) ? ((TCUR) + 4) : (C - 1);                  \
          PX = *(const f32x4*)&xgb[(size_t)pf * G_ + hu * 4]; }                \
        if (q == 0) {                                                          \
            h_u16[PW][hu] = f2bf(hnv);                                         \
            size_t off = ((size_t)b * T_ + (size_t)(t0 + (TCUR))) * H_ + hu;   \
            hs[off] = hnv; cs[off] = c;                                        \
        }                                                                      \
        asm volatile("s_waitcnt lgkmcnt(0)\n\ts_barrier" ::: "memory");        \
    }

    // NOTE: PX used as float4-like; rename accessors via f32x4 indexing
#undef RNN_STEP
#define RNN_STEP(PX, TCUR, PR, PW)                                             \
    {                                                                          \
        f32x4 a0 = {0.f, 0.f, 0.f, 0.f};                                       \
        f32x4 a1 = {0.f, 0.f, 0.f, 0.f};                                       \
        f32x4 a2 = {0.f, 0.f, 0.f, 0.f};                                       \
        f32x4 a3 = {0.f, 0.f, 0.f, 0.f};                                       \
        _Pragma("unroll")                                                      \
        for (int kk = 0; kk < 4; ++kk) {                                       \
            v8bf ha = *(const v8bf*)&h_u16[PR][kk * 32 + kb];                  \
            a0 = __builtin_amdgcn_mfma_f32_16x16x32_bf16(ha, whf[kk][0], a0, 0, 0, 0); \
            a1 = __builtin_amdgcn_mfma_f32_16x16x32_bf16(ha, whf[kk][1], a1, 0, 0, 0); \
            a2 = __builtin_amdgcn_mfma_f32_16x16x32_bf16(ha, whf[kk][2], a2, 0, 0, 0); \
            a3 = __builtin_amdgcn_mfma_f32_16x16x32_bf16(ha, whf[kk][3], a3, 0, 0, 0); \
        }                                                                      \
        float iv = sigmoid_(a0[0] + PX[0]);                                    \
        float fv = sigmoid_(a1[0] + PX[1]);                                    \
        float gv = tanh_(a2[0] + PX[2]);                                       \
        float ov = sigmoid_(a3[0] + PX[3]);                                    \
        c = fmaf(fv, c, iv * gv);                                              \
        float hnv = ov * tanh_(c);                                             \
        { int pf = ((TCUR) + 4 < C) ? ((TCUR) + 4) : (C - 1);                  \
          PX = *(const f32x4*)&xgb[(size_t)pf * G_ + hu * 4]; }                \
        if (q == 0) {                                                          \
            h_u16[PW][hu] = f2bf(hnv);                                         \
            size_t off = ((size_t)b * T_ + (size_t)(t0 + (TCUR))) * H_ + hu;   \
            hs[off] = hnv; cs[off] = c;                                        \
        }                                                                      \
        asm volatile("s_waitcnt lgkmcnt(0)\n\ts_barrier" ::: "memory");        \
    }

#pragma unroll 1
    for (int t = 0; t < C; t += 4) {  // C is a multiple of 64
        RNN_STEP(xp0, t,     0, 1)
        RNN_STEP(xp1, t + 1, 1, 0)
        RNN_STEP(xp2, t + 2, 0, 1)
        RNN_STEP(xp3, t + 3, 1, 0)
    }
#undef RNN_STEP

    if (q == 0) cstate[b * H_ + hu] = c;
    // final h in buf 0 (C multiple of 4; last step wrote PW=0)
    if (tid < H_) {
        unsigned ui = ((unsigned)h_u16[0][tid]) << 16;
        float hf; __builtin_memcpy(&hf, &ui, 4);
        hstate[b * H_ + tid] = hf;
    }
}

extern "C" void kernel_launch(void* const* d_in, const int* in_sizes, int n_in,
                              void* d_out, int out_size, void* d_ws, size_t ws_size,
                              hipStream_t stream) {
    const float* x    = (const float*)d_in[0];  // [64,2048,128]
    const float* Wx   = (const float*)d_in[1];  // [128,512]
    const float* Wh   = (const float*)d_in[2];  // [128,512]
    const float* bias = (const float*)d_in[3];  // [512]

    float* hs = (float*)d_out;                         // [64,2048,128]
    float* cs = hs + (size_t)B_ * T_ * H_;             // [64,2048,128]

    float* hstate = (float*)d_ws;                               // [64,128]
    float* cstate = hstate + B_ * H_;                           // [64,128]
    unsigned short* wxt = (unsigned short*)(cstate + B_ * H_);  // [512][128] bf16
    float* xgA = (float*)(wxt + (size_t)G_ * D_);               // buf A
    // buf B placed after buf A once C is known.

    const size_t head_bytes = (size_t)2 * B_ * H_ * 4 + (size_t)G_ * D_ * 2;
    size_t avail = (ws_size > head_bytes) ? (ws_size - head_bytes) : 0;
    const size_t bytes_per_t = (size_t)B_ * G_ * sizeof(float);  // per timestep

    int C = (int)(avail / (2 * bytes_per_t));   // двойной buffer
    if (C > 512) C = 512;                        // 4+ chunks -> overlap
    C &= ~63;
    if (C < 64) C = 64;

    float* xgB = xgA + (size_t)B_ * C * G_;

    wxt_kernel<<<32, 256, 0, stream>>>(Wx, wxt);

    // chunk list
    int nChunks = 0, t0s[64], Cis[64];
    for (int t0 = 0; t0 < T_; t0 += C) {
        t0s[nChunks] = t0;
        Cis[nChunks] = (T_ - t0 < C) ? (T_ - t0) : C;
        ++nChunks;
    }

    // chunk 0 GEMM standalone
    xg_gemm512<<<(B_ * Cis[0]) / 32, 512, 0, stream>>>(x, wxt, bias, xgA, t0s[0], Cis[0]);

    for (int i = 0; i < nChunks; ++i) {
        float* bufCur  = (i & 1) ? xgB : xgA;
        float* bufNext = (i & 1) ? xgA : xgB;
        int hasNext = (i + 1 < nChunks);
        int t0n = hasNext ? t0s[i + 1] : 0;
        int Cn  = hasNext ? Cis[i + 1] : 64;
        int nGemm = hasNext ? (B_ * Cn) / 32 : 0;
        lstm_fused<<<64 + nGemm, 512, 0, stream>>>(
            x, wxt, Wh, bias, hs, cs, hstate, cstate,
            bufCur, bufNext, t0s[i], Cis[i], t0n, Cn);
    }
}